// Round 1
// baseline (1576.859 us; speedup 1.0000x reference)
//
#include <hip/hip_runtime.h>
#include <math.h>

// Problem constants
constexpr int ROWS  = 19456;   // B*C*N = 16*19*64
constexpr int IN_DIM = 200;
constexpr int FREQ  = 101;     // rfft bins
constexpr int VQD   = 64;
constexpr int NEMB  = 8192;

// ---------------- workspace layout ----------------
constexpr size_t align256(size_t x) { return (x + 255) & ~(size_t)255; }
constexpr size_t SZ_TWID = (size_t)IN_DIM * FREQ * sizeof(double);      // 20200 doubles
constexpr size_t OFF_COS  = 0;
constexpr size_t OFF_SIN  = align256(OFF_COS + SZ_TWID);
constexpr size_t SZ_FT    = (size_t)VQD * ROWS * sizeof(float);         // transposed f32 feats [64][ROWS]
constexpr size_t OFF_FTA  = align256(OFF_SIN + SZ_TWID);
constexpr size_t OFF_FTP  = align256(OFF_FTA + SZ_FT);
constexpr size_t SZ_CBT   = (size_t)VQD * NEMB * sizeof(float);         // transposed+normed cb [64][8192]
constexpr size_t OFF_CBTA = align256(OFF_FTP + SZ_FT);
constexpr size_t OFF_CBTP = align256(OFF_CBTA + SZ_CBT);
constexpr size_t SZ_FD    = (size_t)2 * ROWS * VQD * sizeof(double);    // f64 feats [2][ROWS][64]
constexpr size_t OFF_FD   = align256(OFF_CBTP + SZ_CBT);
constexpr size_t SZ_PI    = (size_t)2 * 4 * ROWS * sizeof(int);         // top-2 candidates per z-chunk
constexpr size_t OFF_PI1  = align256(OFF_FD + SZ_FD);
constexpr size_t OFF_PI2  = align256(OFF_PI1 + SZ_PI);

// ---------------- 1. twiddle table (exact integer-reduced angles, f64) ----------------
__global__ void twiddle_kernel(double* __restrict__ cosT, double* __restrict__ sinT) {
    int idx = blockIdx.x * 256 + threadIdx.x;
    if (idx >= IN_DIM * FREQ) return;
    int n = idx / FREQ, k = idx - n * FREQ;
    int r = (n * k) % IN_DIM;
    double cv, sv;
    // exact values where the true twiddle is 0/±1 so that the imaginary part of
    // bin 0 / Nyquist comes out as exact +0.0 (atan2 sign must match numpy)
    if (r == 0)        { cv =  1.0; sv =  0.0; }
    else if (r == 50)  { cv =  0.0; sv = -1.0; }
    else if (r == 100) { cv = -1.0; sv =  0.0; }
    else if (r == 150) { cv =  0.0; sv =  1.0; }
    else {
        double ang = -6.283185307179586476925286766559 * (double)r / (double)IN_DIM;
        cv = cos(ang); sv = sin(ang);
    }
    cosT[idx] = cv; sinT[idx] = sv;
}

// ---------------- 2. DFT + amp/phase + projection (f64), 8 rows per block ----------------
__global__ __launch_bounds__(128) void dft_proj_kernel(
    const float* __restrict__ x, const float* __restrict__ projA, const float* __restrict__ projP,
    const double* __restrict__ cosT, const double* __restrict__ sinT,
    float* __restrict__ ftA, float* __restrict__ ftP, double* __restrict__ featD)
{
    __shared__ __align__(16) float  xsT[IN_DIM * 8];      // [n][r]
    __shared__ double cosL[25 * FREQ];
    __shared__ double sinL[25 * FREQ];
    __shared__ double ampL[8 * FREQ];                     // [r][k]
    __shared__ double phL [8 * FREQ];
    const int tid = threadIdx.x;
    const int r0 = blockIdx.x * 8;

    for (int e = tid; e < 8 * IN_DIM; e += 128) {
        int r = e / IN_DIM, n = e - r * IN_DIM;
        xsT[n * 8 + r] = x[(size_t)(r0 + r) * IN_DIM + n];
    }

    const int k = tid;
    double re[8], im[8];
#pragma unroll
    for (int r = 0; r < 8; ++r) { re[r] = 0.0; im[r] = 0.0; }

    for (int c = 0; c < 8; ++c) {               // 8 chunks of 25 n-values
        __syncthreads();
        for (int e = tid; e < 25 * FREQ; e += 128) {
            cosL[e] = cosT[c * 25 * FREQ + e];
            sinL[e] = sinT[c * 25 * FREQ + e];
        }
        __syncthreads();
        if (k < FREQ) {
            for (int nl = 0; nl < 25; ++nl) {
                double cv = cosL[nl * FREQ + k];
                double sv = sinL[nl * FREQ + k];
                const float4* xp = (const float4*)(xsT + (c * 25 + nl) * 8);
                float4 x0 = xp[0], x1 = xp[1];
                float xv[8] = {x0.x, x0.y, x0.z, x0.w, x1.x, x1.y, x1.z, x1.w};
#pragma unroll
                for (int r = 0; r < 8; ++r) {
                    double xd = (double)xv[r];
                    re[r] += xd * cv;
                    im[r] += xd * sv;
                }
            }
        }
    }
    if (k < FREQ) {
#pragma unroll
        for (int r = 0; r < 8; ++r) {
            ampL[r * FREQ + k] = sqrt(re[r] * re[r] + im[r] * im[r]);
            phL [r * FREQ + k] = atan2(im[r], re[r]);
        }
    }
    __syncthreads();

    // projection: lanes 0..63 -> amp, 64..127 -> phase
    const int d = tid & 63, which = tid >> 6;
    const float*  proj = which ? projP : projA;
    const double* src  = which ? phL : ampL;
    double acc[8];
#pragma unroll
    for (int r = 0; r < 8; ++r) acc[r] = 0.0;
    for (int kk = 0; kk < FREQ; ++kk) {
        double p = (double)proj[kk * VQD + d];
#pragma unroll
        for (int r = 0; r < 8; ++r) acc[r] += src[r * FREQ + kk] * p;
    }
    float*  ft = which ? ftP : ftA;
    double* fd = featD + (size_t)which * ROWS * VQD;
#pragma unroll
    for (int r = 0; r < 8; ++r) {
        ft[(size_t)d * ROWS + r0 + r] = (float)acc[r];
        fd[(size_t)(r0 + r) * VQD + d] = acc[r];
    }
}

// ---------------- 3. codebook: transpose + fold 1/||cb|| (f64 norm) ----------------
__global__ __launch_bounds__(256) void cb_prep_kernel(
    const float* __restrict__ cbA, const float* __restrict__ cbP,
    float* __restrict__ cbTA, float* __restrict__ cbTP)
{
    __shared__ float tile[64 * 65];
    __shared__ float inv[64];
    const int tid = threadIdx.x;
    const int which = blockIdx.x >> 7;
    const int m0 = (blockIdx.x & 127) * 64;
    const float* cb  = which ? cbP  : cbA;
    float*       out = which ? cbTP : cbTA;
    for (int e = tid; e < 4096; e += 256) {
        int mt = e >> 6, d = e & 63;
        tile[mt * 65 + d] = cb[(size_t)(m0 + mt) * VQD + d];
    }
    __syncthreads();
    if (tid < 64) {
        double s = 0.0;
        for (int d2 = 0; d2 < 64; ++d2) { double v = (double)tile[tid * 65 + d2]; s += v * v; }
        inv[tid] = (float)(1.0 / sqrt(s));
    }
    __syncthreads();
    for (int e = tid; e < 4096; e += 256) {
        int d = e >> 6, mt = e & 63;
        out[(size_t)d * NEMB + m0 + mt] = tile[mt * 65 + d] * inv[mt];
    }
}

// ---------------- 4. fp32 sim + per-chunk top-2 argmax ----------------
// grid: (152 row-tiles, 2 features, 4 code-chunks of 2048). 128 rows x 2048 codes per block.
// 256 threads as 16(tr) x 16(tc), each owning an 8x8 register tile.
__global__ __launch_bounds__(256) void argmax_kernel(
    const float* __restrict__ ftA, const float* __restrict__ ftP,
    const float* __restrict__ cbTA, const float* __restrict__ cbTP,
    int* __restrict__ pi1, int* __restrict__ pi2)
{
    __shared__ __align__(16) float featL[64 * 128];   // [d][r]
    __shared__ __align__(16) float codeL[64 * 128];   // [d][c]
    const int tid = threadIdx.x;
    const int f = blockIdx.y, z = blockIdx.z;
    const int r0 = blockIdx.x * 128;
    const float* ft  = f ? ftP  : ftA;
    const float* cbT = f ? cbTP : cbTA;

    for (int e = tid; e < 8192; e += 256)
        featL[e] = ft[(size_t)(e >> 7) * ROWS + r0 + (e & 127)];

    const int tr = tid & 15, tc = tid >> 4;
    float b1v[8], b2v[8]; int b1i[8], b2i[8];
#pragma unroll
    for (int i = 0; i < 8; ++i) { b1v[i] = -INFINITY; b2v[i] = -INFINITY; b1i[i] = 0; b2i[i] = 0; }

    for (int it = 0; it < 16; ++it) {
        const int c0 = z * 2048 + it * 128;
        __syncthreads();
        for (int e = tid; e < 8192; e += 256)
            codeL[e] = cbT[(size_t)(e >> 7) * NEMB + c0 + (e & 127)];
        __syncthreads();

        float acc[8][8];
#pragma unroll
        for (int i = 0; i < 8; ++i)
#pragma unroll
            for (int j = 0; j < 8; ++j) acc[i][j] = 0.0f;

#pragma unroll 8
        for (int d = 0; d < 64; ++d) {
            const float4* fa = (const float4*)(featL + d * 128 + tr * 8);
            const float4* fb = (const float4*)(codeL + d * 128 + tc * 8);
            float4 a0 = fa[0], a1 = fa[1];
            float4 b0 = fb[0], b1 = fb[1];
            float av[8] = {a0.x, a0.y, a0.z, a0.w, a1.x, a1.y, a1.z, a1.w};
            float bv[8] = {b0.x, b0.y, b0.z, b0.w, b1.x, b1.y, b1.z, b1.w};
#pragma unroll
            for (int i = 0; i < 8; ++i)
#pragma unroll
                for (int j = 0; j < 8; ++j)
                    acc[i][j] = fmaf(av[i], bv[j], acc[i][j]);
        }
        // top-2 update (ascending code order + strict '>' keeps lowest index on ties)
#pragma unroll
        for (int j = 0; j < 8; ++j) {
            const int idx = c0 + tc * 8 + j;
#pragma unroll
            for (int i = 0; i < 8; ++i) {
                float v = acc[i][j];
                if (v > b1v[i])      { b2v[i] = b1v[i]; b2i[i] = b1i[i]; b1v[i] = v; b1i[i] = idx; }
                else if (v > b2v[i]) { b2v[i] = v; b2i[i] = idx; }
            }
        }
    }
    __syncthreads();
    // block reduction: 16 tc-candidates x2 per row -> top-2 of 2048 codes
    float* redv = featL;           // [128][32]
    int*   redi = (int*)codeL;
#pragma unroll
    for (int i = 0; i < 8; ++i) {
        int row = tr * 8 + i;
        redv[row * 32 + tc * 2]     = b1v[i];  redi[row * 32 + tc * 2]     = b1i[i];
        redv[row * 32 + tc * 2 + 1] = b2v[i];  redi[row * 32 + tc * 2 + 1] = b2i[i];
    }
    __syncthreads();
    if (tid < 128) {
        int row = tid;
        float v1 = -INFINITY, v2 = -INFINITY; int i1 = 0x7fffffff, i2 = 0x7fffffff;
        for (int e = 0; e < 32; ++e) {
            float v = redv[row * 32 + e]; int id = redi[row * 32 + e];
            if (v > v1 || (v == v1 && id < i1)) { v2 = v1; i2 = i1; v1 = v; i1 = id; }
            else if (v > v2 || (v == v2 && id < i2)) { v2 = v; i2 = id; }
        }
        size_t p = ((size_t)(f * 4 + z)) * ROWS + r0 + row;
        pi1[p] = i1; pi2[p] = i2;
    }
}

// ---------------- 5. f64 rescore of the 8 candidates/row, emit int32 index ----------------
__global__ __launch_bounds__(256) void rescore_kernel(
    const double* __restrict__ featD,
    const float* __restrict__ cbA, const float* __restrict__ cbP,
    const int* __restrict__ pi1, const int* __restrict__ pi2,
    int* __restrict__ out)
{
    const int tid = threadIdx.x;
    const int lane = tid & 63, wave = tid >> 6;
    const int task = blockIdx.x * 4 + wave;           // 0 .. 2*ROWS-1
    const int f = task / ROWS;
    const int row = task - f * ROWS;
    const float* cb = f ? cbP : cbA;
    const double fd = featD[((size_t)f * ROWS + row) * VQD + lane];
    double bestv = -1.0e300; int besti = 0x7fffffff;
    for (int c = 0; c < 8; ++c) {
        int z = c >> 1;
        size_t p = ((size_t)(f * 4 + z)) * ROWS + row;
        int idx = (c & 1) ? pi2[p] : pi1[p];
        double cv = (double)cb[(size_t)idx * VQD + lane];
        double t = fd * cv, s = cv * cv;
        for (int m = 32; m >= 1; m >>= 1) {
            t += __shfl_xor(t, m, 64);
            s += __shfl_xor(s, m, 64);
        }
        double sim = t / sqrt(s);
        if (sim > bestv || (sim == bestv && idx < besti)) { bestv = sim; besti = idx; }
    }
    if (lane == 0) out[task] = besti;
}

// ---------------- launch ----------------
extern "C" void kernel_launch(void* const* d_in, const int* in_sizes, int n_in,
                              void* d_out, int out_size, void* d_ws, size_t ws_size,
                              hipStream_t stream)
{
    const float* x     = (const float*)d_in[0];
    const float* projA = (const float*)d_in[1];
    const float* projP = (const float*)d_in[2];
    const float* cbA   = (const float*)d_in[3];
    const float* cbP   = (const float*)d_in[4];

    char* ws = (char*)d_ws;
    double* cosT  = (double*)(ws + OFF_COS);
    double* sinT  = (double*)(ws + OFF_SIN);
    float*  ftA   = (float*) (ws + OFF_FTA);
    float*  ftP   = (float*) (ws + OFF_FTP);
    float*  cbTA  = (float*) (ws + OFF_CBTA);
    float*  cbTP  = (float*) (ws + OFF_CBTP);
    double* featD = (double*)(ws + OFF_FD);
    int*    pi1   = (int*)   (ws + OFF_PI1);
    int*    pi2   = (int*)   (ws + OFF_PI2);

    twiddle_kernel<<<(IN_DIM * FREQ + 255) / 256, 256, 0, stream>>>(cosT, sinT);
    dft_proj_kernel<<<ROWS / 8, 128, 0, stream>>>(x, projA, projP, cosT, sinT, ftA, ftP, featD);
    cb_prep_kernel<<<256, 256, 0, stream>>>(cbA, cbP, cbTA, cbTP);
    argmax_kernel<<<dim3(ROWS / 128, 2, 4), 256, 0, stream>>>(ftA, ftP, cbTA, cbTP, pi1, pi2);
    rescore_kernel<<<(2 * ROWS) / 4, 256, 0, stream>>>(featD, cbA, cbP, pi1, pi2, (int*)d_out);
}

// Round 2
// 552.352 us; speedup vs baseline: 2.8548x; 2.8548x over previous
//
#include <hip/hip_runtime.h>
#include <math.h>

// Problem constants
constexpr int ROWS  = 19456;   // B*C*N = 16*19*64
constexpr int IN_DIM = 200;
constexpr int FREQ  = 101;     // rfft bins
constexpr int VQD   = 64;
constexpr int NEMB  = 8192;

typedef __attribute__((ext_vector_type(8))) short short8;   // 8 bf16 = 4 VGPRs
typedef __attribute__((ext_vector_type(4))) float floatx4;

__device__ __forceinline__ unsigned short f2bf(float v) {   // RTN-even fp32->bf16
    unsigned int u = __builtin_bit_cast(unsigned int, v);
    unsigned int r = u + 0x7fffu + ((u >> 16) & 1u);
    return (unsigned short)(r >> 16);
}
__device__ __forceinline__ float bf2f(unsigned short b) {
    unsigned int u = ((unsigned int)b) << 16;
    return __builtin_bit_cast(float, u);
}

// ---------------- workspace layout ----------------
constexpr size_t align256(size_t x) { return (x + 255) & ~(size_t)255; }
constexpr size_t SZ_TWID = (size_t)IN_DIM * FREQ * sizeof(double);
constexpr size_t OFF_COS  = 0;
constexpr size_t OFF_SIN  = align256(OFF_COS + SZ_TWID);
constexpr size_t SZ_FB    = (size_t)2 * ROWS * VQD * sizeof(unsigned short); // bf16 feats [2][ROWS][64]
constexpr size_t OFF_FTH  = align256(OFF_SIN + SZ_TWID);
constexpr size_t OFF_FTL  = align256(OFF_FTH + SZ_FB);
constexpr size_t SZ_CBB   = (size_t)2 * NEMB * VQD * sizeof(unsigned short); // bf16 codes [2][8192][64]
constexpr size_t OFF_CBH  = align256(OFF_FTL + SZ_FB);
constexpr size_t OFF_CBL  = align256(OFF_CBH + SZ_CBB);
constexpr size_t SZ_FD    = (size_t)2 * ROWS * VQD * sizeof(double);         // f64 feats
constexpr size_t OFF_FD   = align256(OFF_CBL + SZ_CBB);
constexpr size_t SZ_PI    = (size_t)2 * 4 * ROWS * sizeof(int);
constexpr size_t OFF_PI1  = align256(OFF_FD + SZ_FD);
constexpr size_t OFF_PI2  = align256(OFF_PI1 + SZ_PI);

// ---------------- 1. twiddle table (exact integer-reduced angles, f64) ----------------
__global__ void twiddle_kernel(double* __restrict__ cosT, double* __restrict__ sinT) {
    int idx = blockIdx.x * 256 + threadIdx.x;
    if (idx >= IN_DIM * FREQ) return;
    int n = idx / FREQ, k = idx - n * FREQ;
    int r = (n * k) % IN_DIM;
    double cv, sv;
    if (r == 0)        { cv =  1.0; sv =  0.0; }
    else if (r == 50)  { cv =  0.0; sv = -1.0; }
    else if (r == 100) { cv = -1.0; sv =  0.0; }
    else if (r == 150) { cv =  0.0; sv =  1.0; }
    else {
        double ang = -6.283185307179586476925286766559 * (double)r / (double)IN_DIM;
        cv = cos(ang); sv = sin(ang);
    }
    cosT[idx] = cv; sinT[idx] = sv;
}

// ---------------- 2. DFT + amp/phase + projection (f64), 8 rows per block ----------------
__global__ __launch_bounds__(128) void dft_proj_kernel(
    const float* __restrict__ x, const float* __restrict__ projA, const float* __restrict__ projP,
    const double* __restrict__ cosT, const double* __restrict__ sinT,
    unsigned short* __restrict__ ftH, unsigned short* __restrict__ ftL, double* __restrict__ featD)
{
    __shared__ __align__(16) float  xsT[IN_DIM * 8];      // [n][r]
    __shared__ double cosL[25 * FREQ];
    __shared__ double sinL[25 * FREQ];
    __shared__ double ampL[8 * FREQ];                     // [r][k]
    __shared__ double phL [8 * FREQ];
    const int tid = threadIdx.x;
    const int r0 = blockIdx.x * 8;

    for (int e = tid; e < 8 * IN_DIM; e += 128) {
        int r = e / IN_DIM, n = e - r * IN_DIM;
        xsT[n * 8 + r] = x[(size_t)(r0 + r) * IN_DIM + n];
    }

    const int k = tid;
    double re[8], im[8];
#pragma unroll
    for (int r = 0; r < 8; ++r) { re[r] = 0.0; im[r] = 0.0; }

    for (int c = 0; c < 8; ++c) {               // 8 chunks of 25 n-values
        __syncthreads();
        for (int e = tid; e < 25 * FREQ; e += 128) {
            cosL[e] = cosT[c * 25 * FREQ + e];
            sinL[e] = sinT[c * 25 * FREQ + e];
        }
        __syncthreads();
        if (k < FREQ) {
            for (int nl = 0; nl < 25; ++nl) {
                double cv = cosL[nl * FREQ + k];
                double sv = sinL[nl * FREQ + k];
                const float4* xp = (const float4*)(xsT + (c * 25 + nl) * 8);
                float4 x0 = xp[0], x1 = xp[1];
                float xv[8] = {x0.x, x0.y, x0.z, x0.w, x1.x, x1.y, x1.z, x1.w};
#pragma unroll
                for (int r = 0; r < 8; ++r) {
                    double xd = (double)xv[r];
                    re[r] += xd * cv;
                    im[r] += xd * sv;
                }
            }
        }
    }
    if (k < FREQ) {
#pragma unroll
        for (int r = 0; r < 8; ++r) {
            ampL[r * FREQ + k] = sqrt(re[r] * re[r] + im[r] * im[r]);
            phL [r * FREQ + k] = atan2(im[r], re[r]);
        }
    }
    __syncthreads();

    // projection: lanes 0..63 -> amp, 64..127 -> phase
    const int d = tid & 63, which = tid >> 6;
    const float*  proj = which ? projP : projA;
    const double* src  = which ? phL : ampL;
    double acc[8];
#pragma unroll
    for (int r = 0; r < 8; ++r) acc[r] = 0.0;
    for (int kk = 0; kk < FREQ; ++kk) {
        double p = (double)proj[kk * VQD + d];
#pragma unroll
        for (int r = 0; r < 8; ++r) acc[r] += src[r * FREQ + kk] * p;
    }
#pragma unroll
    for (int r = 0; r < 8; ++r) {
        size_t rowi = (size_t)which * ROWS + r0 + r;
        float vf = (float)acc[r];
        unsigned short hb = f2bf(vf);
        unsigned short lb = f2bf(vf - bf2f(hb));
        ftH[rowi * VQD + d] = hb;
        ftL[rowi * VQD + d] = lb;
        featD[rowi * VQD + d] = acc[r];
    }
}

// ---------------- 3. codebook: fold 1/||cb|| (f64 norm) + bf16 hi/lo split ----------------
__global__ __launch_bounds__(256) void cb_prep_kernel(
    const float* __restrict__ cbA, const float* __restrict__ cbP,
    unsigned short* __restrict__ cbH, unsigned short* __restrict__ cbL)
{
    __shared__ float tile[64 * 65];
    __shared__ float inv[64];
    const int tid = threadIdx.x;
    const int which = blockIdx.y;
    const int m0 = blockIdx.x * 64;
    const float* cb = which ? cbP : cbA;
    for (int e = tid; e < 4096; e += 256) {
        int c = e >> 6, d = e & 63;
        tile[c * 65 + d] = cb[(size_t)(m0 + c) * VQD + d];
    }
    __syncthreads();
    if (tid < 64) {
        double s = 0.0;
        for (int d2 = 0; d2 < 64; ++d2) { double v = (double)tile[tid * 65 + d2]; s += v * v; }
        inv[tid] = (float)(1.0 / sqrt(s));
    }
    __syncthreads();
    for (int e = tid; e < 4096; e += 256) {
        int c = e >> 6, d = e & 63;
        float v = tile[c * 65 + d] * inv[c];
        unsigned short hb = f2bf(v);
        unsigned short lb = f2bf(v - bf2f(hb));
        size_t o = ((size_t)which * NEMB + m0 + c) * VQD + d;
        cbH[o] = hb; cbL[o] = lb;
    }
}

// ---------------- 4. bf16x3 MFMA sim + per-chunk top-2 ----------------
// grid (152, 2, 4): 128 rows x 2048 codes per block; 4 waves, each wave 32 rows.
// LDS code tile: 128 codes x 64 dims, hi+lo, row stride padded to 144 B (2-way max alias).
#define MFMA(a, b, c) __builtin_amdgcn_mfma_f32_16x16x32_bf16(a, b, c, 0, 0, 0)
#define UPD(val, s) do { float _v = (val); \
    bool _c1 = _v > b1v[s]; bool _c2 = _v > b2v[s]; \
    b2v[s] = _c1 ? b1v[s] : (_c2 ? _v : b2v[s]); \
    b2i[s] = _c1 ? b1i[s] : (_c2 ? idx : b2i[s]); \
    b1v[s] = _c1 ? _v : b1v[s]; \
    b1i[s] = _c1 ? idx : b1i[s]; } while (0)

__global__ __launch_bounds__(256, 3) void argmax_kernel(
    const unsigned short* __restrict__ ftH, const unsigned short* __restrict__ ftL,
    const unsigned short* __restrict__ cbH, const unsigned short* __restrict__ cbL,
    int* __restrict__ pi1, int* __restrict__ pi2)
{
    __shared__ __align__(16) char lds[2 * 128 * 144];     // 36864 B
    const int tid = threadIdx.x;
    const int f = blockIdx.y, z = blockIdx.z;
    const int r0 = blockIdx.x * 128;
    const int w = tid >> 6, lane = tid & 63;
    const int q = lane >> 4, cl = lane & 15;

    const unsigned short* ftHb = ftH + (size_t)f * ROWS * VQD;
    const unsigned short* ftLb = ftL + (size_t)f * ROWS * VQD;
    const unsigned short* cbHb = cbH + (size_t)f * NEMB * VQD;
    const unsigned short* cbLb = cbL + (size_t)f * NEMB * VQD;

    // A fragments: rows r0 + w*32 + {cl, 16+cl}; per-lane k = kb*32 + q*8 .. +8
    short8 aH00, aH01, aH10, aH11, aL00, aL01, aL10, aL11;
    {
        const size_t baseA = (size_t)(r0 + w * 32 + cl) * VQD + q * 8;
        const size_t baseB = baseA + (size_t)16 * VQD;
        aH00 = *(const short8*)(ftHb + baseA);
        aH01 = *(const short8*)(ftHb + baseA + 32);
        aH10 = *(const short8*)(ftHb + baseB);
        aH11 = *(const short8*)(ftHb + baseB + 32);
        aL00 = *(const short8*)(ftLb + baseA);
        aL01 = *(const short8*)(ftLb + baseA + 32);
        aL10 = *(const short8*)(ftLb + baseB);
        aL11 = *(const short8*)(ftLb + baseB + 32);
    }

    float b1v[8], b2v[8]; int b1i[8], b2i[8];
#pragma unroll
    for (int s = 0; s < 8; ++s) { b1v[s] = -INFINITY; b2v[s] = -INFINITY; b1i[s] = 0; b2i[s] = 0; }

    const int cstage = tid >> 1, hstage = tid & 1;
    const size_t gsoff = (size_t)(z * 2048) * VQD;

    for (int it = 0; it < 16; ++it) {
        __syncthreads();
        {   // stage 128 codes (hi+lo): thread -> (code=tid>>1, 32-elem half=tid&1)
            const unsigned short* sH = cbHb + gsoff + (size_t)(it * 128 + cstage) * VQD + hstage * 32;
            const unsigned short* sL = cbLb + gsoff + (size_t)(it * 128 + cstage) * VQD + hstage * 32;
            char* dH = lds + cstage * 144 + hstage * 64;
            char* dL = dH + 128 * 144;
            floatx4 h0 = ((const floatx4*)sH)[0], h1 = ((const floatx4*)sH)[1];
            floatx4 h2 = ((const floatx4*)sH)[2], h3 = ((const floatx4*)sH)[3];
            floatx4 l0 = ((const floatx4*)sL)[0], l1 = ((const floatx4*)sL)[1];
            floatx4 l2 = ((const floatx4*)sL)[2], l3 = ((const floatx4*)sL)[3];
            ((floatx4*)dH)[0] = h0; ((floatx4*)dH)[1] = h1; ((floatx4*)dH)[2] = h2; ((floatx4*)dH)[3] = h3;
            ((floatx4*)dL)[0] = l0; ((floatx4*)dL)[1] = l1; ((floatx4*)dL)[2] = l2; ((floatx4*)dL)[3] = l3;
        }
        __syncthreads();

        const int cbase = z * 2048 + it * 128;
#pragma unroll
        for (int nt = 0; nt < 8; ++nt) {
            const char* pB = lds + (nt * 16 + cl) * 144 + q * 16;
            short8 bH0 = *(const short8*)(pB);
            short8 bH1 = *(const short8*)(pB + 64);
            short8 bL0 = *(const short8*)(pB + 128 * 144);
            short8 bL1 = *(const short8*)(pB + 128 * 144 + 64);

            floatx4 acc0 = {0.f, 0.f, 0.f, 0.f};
            floatx4 acc1 = {0.f, 0.f, 0.f, 0.f};
            acc0 = MFMA(aH00, bH0, acc0);  acc1 = MFMA(aH10, bH0, acc1);
            acc0 = MFMA(aH01, bH1, acc0);  acc1 = MFMA(aH11, bH1, acc1);
            acc0 = MFMA(aH00, bL0, acc0);  acc1 = MFMA(aH10, bL0, acc1);
            acc0 = MFMA(aH01, bL1, acc0);  acc1 = MFMA(aH11, bL1, acc1);
            acc0 = MFMA(aL00, bH0, acc0);  acc1 = MFMA(aL10, bH0, acc1);
            acc0 = MFMA(aL01, bH1, acc0);  acc1 = MFMA(aL11, bH1, acc1);

            const int idx = cbase + nt * 16 + cl;
#pragma unroll
            for (int i = 0; i < 4; ++i) { UPD(acc0[i], i); UPD(acc1[i], 4 + i); }
        }
    }

    // block reduction: per-lane top-2 (col-slice cl) -> per-row top-2 of 2048
    __syncthreads();
    float* redv = (float*)lds;
    int*   redi = (int*)(lds + 128 * 33 * 4);
#pragma unroll
    for (int s = 0; s < 8; ++s) {
        int rowl = w * 32 + ((s & 4) << 2) + q * 4 + (s & 3);   // +16 when s>=4
        int base = rowl * 33 + cl * 2;
        redv[base]     = b1v[s]; redi[base]     = b1i[s];
        redv[base + 1] = b2v[s]; redi[base + 1] = b2i[s];
    }
    __syncthreads();
    if (tid < 128) {
        float v1 = -INFINITY, v2 = -INFINITY; int i1 = 0x7fffffff, i2 = 0x7fffffff;
        for (int e = 0; e < 32; ++e) {
            float v = redv[tid * 33 + e]; int id = redi[tid * 33 + e];
            if (v > v1 || (v == v1 && id < i1)) { v2 = v1; i2 = i1; v1 = v; i1 = id; }
            else if (v > v2 || (v == v2 && id < i2)) { v2 = v; i2 = id; }
        }
        size_t p = ((size_t)(f * 4 + z)) * ROWS + r0 + tid;
        pi1[p] = i1; pi2[p] = i2;
    }
}

// ---------------- 5. f64 rescore of the 8 candidates/row, emit int32 index ----------------
__global__ __launch_bounds__(256) void rescore_kernel(
    const double* __restrict__ featD,
    const float* __restrict__ cbA, const float* __restrict__ cbP,
    const int* __restrict__ pi1, const int* __restrict__ pi2,
    int* __restrict__ out)
{
    const int tid = threadIdx.x;
    const int lane = tid & 63, wave = tid >> 6;
    const int task = blockIdx.x * 4 + wave;           // 0 .. 2*ROWS-1
    const int f = task / ROWS;
    const int row = task - f * ROWS;
    const float* cb = f ? cbP : cbA;
    const double fd = featD[((size_t)f * ROWS + row) * VQD + lane];
    double bestv = -1.0e300; int besti = 0x7fffffff;
    for (int c = 0; c < 8; ++c) {
        int z = c >> 1;
        size_t p = ((size_t)(f * 4 + z)) * ROWS + row;
        int idx = (c & 1) ? pi2[p] : pi1[p];
        double cv = (double)cb[(size_t)idx * VQD + lane];
        double t = fd * cv, s = cv * cv;
        for (int m = 32; m >= 1; m >>= 1) {
            t += __shfl_xor(t, m, 64);
            s += __shfl_xor(s, m, 64);
        }
        double sim = t / sqrt(s);
        if (sim > bestv || (sim == bestv && idx < besti)) { bestv = sim; besti = idx; }
    }
    if (lane == 0) out[task] = besti;
}

// ---------------- launch ----------------
extern "C" void kernel_launch(void* const* d_in, const int* in_sizes, int n_in,
                              void* d_out, int out_size, void* d_ws, size_t ws_size,
                              hipStream_t stream)
{
    const float* x     = (const float*)d_in[0];
    const float* projA = (const float*)d_in[1];
    const float* projP = (const float*)d_in[2];
    const float* cbA   = (const float*)d_in[3];
    const float* cbP   = (const float*)d_in[4];

    char* ws = (char*)d_ws;
    double*         cosT  = (double*)(ws + OFF_COS);
    double*         sinT  = (double*)(ws + OFF_SIN);
    unsigned short* ftH   = (unsigned short*)(ws + OFF_FTH);
    unsigned short* ftL   = (unsigned short*)(ws + OFF_FTL);
    unsigned short* cbHp  = (unsigned short*)(ws + OFF_CBH);
    unsigned short* cbLp  = (unsigned short*)(ws + OFF_CBL);
    double*         featD = (double*)(ws + OFF_FD);
    int*            pi1   = (int*)(ws + OFF_PI1);
    int*            pi2   = (int*)(ws + OFF_PI2);

    twiddle_kernel<<<(IN_DIM * FREQ + 255) / 256, 256, 0, stream>>>(cosT, sinT);
    dft_proj_kernel<<<ROWS / 8, 128, 0, stream>>>(x, projA, projP, cosT, sinT, ftH, ftL, featD);
    cb_prep_kernel<<<dim3(NEMB / 64, 2), 256, 0, stream>>>(cbA, cbP, cbHp, cbLp);
    argmax_kernel<<<dim3(ROWS / 128, 2, 4), 256, 0, stream>>>(ftH, ftL, cbHp, cbLp, pi1, pi2);
    rescore_kernel<<<(2 * ROWS) / 4, 256, 0, stream>>>(featD, cbA, cbP, pi1, pi2, (int*)d_out);
}

// Round 3
// 395.269 us; speedup vs baseline: 3.9893x; 1.3974x over previous
//
#include <hip/hip_runtime.h>
#include <math.h>

// Problem constants
constexpr int ROWS  = 19456;   // B*C*N = 16*19*64
constexpr int IN_DIM = 200;
constexpr int FREQ  = 101;     // rfft bins
constexpr int VQD   = 64;
constexpr int NEMB  = 8192;

typedef __attribute__((ext_vector_type(8))) short short8;   // 8 bf16 = 4 VGPRs
typedef __attribute__((ext_vector_type(4))) float floatx4;

__device__ __forceinline__ unsigned short f2bf(float v) {   // RTN-even fp32->bf16
    unsigned int u = __builtin_bit_cast(unsigned int, v);
    unsigned int r = u + 0x7fffu + ((u >> 16) & 1u);
    return (unsigned short)(r >> 16);
}
__device__ __forceinline__ float bf2f(unsigned short b) {
    unsigned int u = ((unsigned int)b) << 16;
    return __builtin_bit_cast(float, u);
}

// ---------------- workspace layout ----------------
constexpr size_t align256(size_t x) { return (x + 255) & ~(size_t)255; }
constexpr size_t SZ_TAB = (size_t)IN_DIM * sizeof(double);                   // 200 doubles
constexpr size_t OFF_COS  = 0;
constexpr size_t OFF_SIN  = align256(OFF_COS + SZ_TAB);
constexpr size_t SZ_FB    = (size_t)2 * ROWS * VQD * sizeof(unsigned short); // bf16 feats [2][ROWS][64]
constexpr size_t OFF_FTH  = align256(OFF_SIN + SZ_TAB);
constexpr size_t OFF_FTL  = align256(OFF_FTH + SZ_FB);
constexpr size_t SZ_CBB   = (size_t)2 * NEMB * VQD * sizeof(unsigned short); // bf16 codes [2][8192][64]
constexpr size_t OFF_CBH  = align256(OFF_FTL + SZ_FB);
constexpr size_t OFF_CBL  = align256(OFF_CBH + SZ_CBB);
constexpr size_t SZ_FD    = (size_t)2 * ROWS * VQD * sizeof(double);         // f64 feats
constexpr size_t OFF_FD   = align256(OFF_CBL + SZ_CBB);
constexpr size_t SZ_PI    = (size_t)2 * 4 * ROWS * sizeof(int);
constexpr size_t OFF_PI1  = align256(OFF_FD + SZ_FD);
constexpr size_t OFF_PI2  = align256(OFF_PI1 + SZ_PI);

// ---------------- 1. periodic twiddle tables: cos/sin(-2*pi*r/200), r=0..199 ----------------
// Same libm calls + exact quarter-point entries as the validated round-1 table, so the
// DFT accumulates bitwise-identical values.
__global__ void twiddle_kernel(double* __restrict__ cosT, double* __restrict__ sinT) {
    int r = blockIdx.x * 256 + threadIdx.x;
    if (r >= IN_DIM) return;
    double cv, sv;
    if (r == 0)        { cv =  1.0; sv =  0.0; }
    else if (r == 50)  { cv =  0.0; sv = -1.0; }
    else if (r == 100) { cv = -1.0; sv =  0.0; }
    else if (r == 150) { cv =  0.0; sv =  1.0; }
    else {
        double ang = -6.283185307179586476925286766559 * (double)r / (double)IN_DIM;
        cv = cos(ang); sv = sin(ang);
    }
    cosT[r] = cv; sinT[r] = sv;
}

// ---------------- 2. DFT + amp/phase + projection (f64), 8 rows per block ----------------
// Twiddles via 200-entry periodic LDS tables, incremental index rc = (n*k) mod 200.
__global__ __launch_bounds__(128, 3) void dft_proj_kernel(
    const float* __restrict__ x, const float* __restrict__ projA, const float* __restrict__ projP,
    const double* __restrict__ cosTG, const double* __restrict__ sinTG,
    unsigned short* __restrict__ ftH, unsigned short* __restrict__ ftL, double* __restrict__ featD)
{
    __shared__ __align__(16) float  xsT[IN_DIM * 8];      // [n][r]  6.4 KB
    __shared__ double costab[IN_DIM];                     // 1.6 KB
    __shared__ double sintab[IN_DIM];                     // 1.6 KB
    __shared__ double ampL[8 * FREQ];                     // [r][k]  6.5 KB
    __shared__ double phL [8 * FREQ];                     //         6.5 KB
    const int tid = threadIdx.x;
    const int r0 = blockIdx.x * 8;

    for (int e = tid; e < 8 * IN_DIM; e += 128) {
        int r = e / IN_DIM, n = e - r * IN_DIM;
        xsT[n * 8 + r] = x[(size_t)(r0 + r) * IN_DIM + n];
    }
    for (int e = tid; e < IN_DIM; e += 128) {
        costab[e] = cosTG[e];
        sintab[e] = sinTG[e];
    }
    __syncthreads();

    const int k = tid;
    double re[8], im[8];
#pragma unroll
    for (int r = 0; r < 8; ++r) { re[r] = 0.0; im[r] = 0.0; }

    if (k < FREQ) {
        int rc = 0;                       // (n*k) mod 200, n starts at 0
        for (int n = 0; n < IN_DIM; ++n) {
            double cv = costab[rc];
            double sv = sintab[rc];
            const float4* xp = (const float4*)(xsT + n * 8);
            float4 x0 = xp[0], x1 = xp[1];
            float xv[8] = {x0.x, x0.y, x0.z, x0.w, x1.x, x1.y, x1.z, x1.w};
#pragma unroll
            for (int r = 0; r < 8; ++r) {
                double xd = (double)xv[r];
                re[r] += xd * cv;
                im[r] += xd * sv;
            }
            rc += k;
            if (rc >= IN_DIM) rc -= IN_DIM;
        }
#pragma unroll
        for (int r = 0; r < 8; ++r) {
            ampL[r * FREQ + k] = sqrt(re[r] * re[r] + im[r] * im[r]);
            phL [r * FREQ + k] = atan2(im[r], re[r]);
        }
    }
    __syncthreads();

    // projection: lanes 0..63 -> amp, 64..127 -> phase (identical to validated round-1 code)
    const int d = tid & 63, which = tid >> 6;
    const float*  proj = which ? projP : projA;
    const double* src  = which ? phL : ampL;
    double acc[8];
#pragma unroll
    for (int r = 0; r < 8; ++r) acc[r] = 0.0;
    for (int kk = 0; kk < FREQ; ++kk) {
        double p = (double)proj[kk * VQD + d];
#pragma unroll
        for (int r = 0; r < 8; ++r) acc[r] += src[r * FREQ + kk] * p;
    }
#pragma unroll
    for (int r = 0; r < 8; ++r) {
        size_t rowi = (size_t)which * ROWS + r0 + r;
        float vf = (float)acc[r];
        unsigned short hb = f2bf(vf);
        unsigned short lb = f2bf(vf - bf2f(hb));
        ftH[rowi * VQD + d] = hb;
        ftL[rowi * VQD + d] = lb;
        featD[rowi * VQD + d] = acc[r];
    }
}

// ---------------- 3. codebook: fold 1/||cb|| (f64 norm) + bf16 hi/lo split ----------------
__global__ __launch_bounds__(256) void cb_prep_kernel(
    const float* __restrict__ cbA, const float* __restrict__ cbP,
    unsigned short* __restrict__ cbH, unsigned short* __restrict__ cbL)
{
    __shared__ float tile[64 * 65];
    __shared__ float inv[64];
    const int tid = threadIdx.x;
    const int which = blockIdx.y;
    const int m0 = blockIdx.x * 64;
    const float* cb = which ? cbP : cbA;
    for (int e = tid; e < 4096; e += 256) {
        int c = e >> 6, d = e & 63;
        tile[c * 65 + d] = cb[(size_t)(m0 + c) * VQD + d];
    }
    __syncthreads();
    if (tid < 64) {
        double s = 0.0;
        for (int d2 = 0; d2 < 64; ++d2) { double v = (double)tile[tid * 65 + d2]; s += v * v; }
        inv[tid] = (float)(1.0 / sqrt(s));
    }
    __syncthreads();
    for (int e = tid; e < 4096; e += 256) {
        int c = e >> 6, d = e & 63;
        float v = tile[c * 65 + d] * inv[c];
        unsigned short hb = f2bf(v);
        unsigned short lb = f2bf(v - bf2f(hb));
        size_t o = ((size_t)which * NEMB + m0 + c) * VQD + d;
        cbH[o] = hb; cbL[o] = lb;
    }
}

// ---------------- 4. bf16x3 MFMA sim + per-chunk top-2 ----------------
// grid (152, 2, 4): 128 rows x 2048 codes per block; 4 waves, each wave 32 rows.
// LDS code tile: 128 codes x 64 dims, hi+lo, row stride padded to 144 B (2-way max alias).
#define MFMA(a, b, c) __builtin_amdgcn_mfma_f32_16x16x32_bf16(a, b, c, 0, 0, 0)
#define UPD(val, s) do { float _v = (val); \
    bool _c1 = _v > b1v[s]; bool _c2 = _v > b2v[s]; \
    b2v[s] = _c1 ? b1v[s] : (_c2 ? _v : b2v[s]); \
    b2i[s] = _c1 ? b1i[s] : (_c2 ? idx : b2i[s]); \
    b1v[s] = _c1 ? _v : b1v[s]; \
    b1i[s] = _c1 ? idx : b1i[s]; } while (0)

__global__ __launch_bounds__(256, 3) void argmax_kernel(
    const unsigned short* __restrict__ ftH, const unsigned short* __restrict__ ftL,
    const unsigned short* __restrict__ cbH, const unsigned short* __restrict__ cbL,
    int* __restrict__ pi1, int* __restrict__ pi2)
{
    __shared__ __align__(16) char lds[2 * 128 * 144];     // 36864 B
    const int tid = threadIdx.x;
    const int f = blockIdx.y, z = blockIdx.z;
    const int r0 = blockIdx.x * 128;
    const int w = tid >> 6, lane = tid & 63;
    const int q = lane >> 4, cl = lane & 15;

    const unsigned short* ftHb = ftH + (size_t)f * ROWS * VQD;
    const unsigned short* ftLb = ftL + (size_t)f * ROWS * VQD;
    const unsigned short* cbHb = cbH + (size_t)f * NEMB * VQD;
    const unsigned short* cbLb = cbL + (size_t)f * NEMB * VQD;

    // A fragments: rows r0 + w*32 + {cl, 16+cl}; per-lane k = kb*32 + q*8 .. +8
    short8 aH00, aH01, aH10, aH11, aL00, aL01, aL10, aL11;
    {
        const size_t baseA = (size_t)(r0 + w * 32 + cl) * VQD + q * 8;
        const size_t baseB = baseA + (size_t)16 * VQD;
        aH00 = *(const short8*)(ftHb + baseA);
        aH01 = *(const short8*)(ftHb + baseA + 32);
        aH10 = *(const short8*)(ftHb + baseB);
        aH11 = *(const short8*)(ftHb + baseB + 32);
        aL00 = *(const short8*)(ftLb + baseA);
        aL01 = *(const short8*)(ftLb + baseA + 32);
        aL10 = *(const short8*)(ftLb + baseB);
        aL11 = *(const short8*)(ftLb + baseB + 32);
    }

    float b1v[8], b2v[8]; int b1i[8], b2i[8];
#pragma unroll
    for (int s = 0; s < 8; ++s) { b1v[s] = -INFINITY; b2v[s] = -INFINITY; b1i[s] = 0; b2i[s] = 0; }

    const int cstage = tid >> 1, hstage = tid & 1;
    const size_t gsoff = (size_t)(z * 2048) * VQD;

    for (int it = 0; it < 16; ++it) {
        __syncthreads();
        {   // stage 128 codes (hi+lo): thread -> (code=tid>>1, 32-elem half=tid&1)
            const unsigned short* sH = cbHb + gsoff + (size_t)(it * 128 + cstage) * VQD + hstage * 32;
            const unsigned short* sL = cbLb + gsoff + (size_t)(it * 128 + cstage) * VQD + hstage * 32;
            char* dH = lds + cstage * 144 + hstage * 64;
            char* dL = dH + 128 * 144;
            floatx4 h0 = ((const floatx4*)sH)[0], h1 = ((const floatx4*)sH)[1];
            floatx4 h2 = ((const floatx4*)sH)[2], h3 = ((const floatx4*)sH)[3];
            floatx4 l0 = ((const floatx4*)sL)[0], l1 = ((const floatx4*)sL)[1];
            floatx4 l2 = ((const floatx4*)sL)[2], l3 = ((const floatx4*)sL)[3];
            ((floatx4*)dH)[0] = h0; ((floatx4*)dH)[1] = h1; ((floatx4*)dH)[2] = h2; ((floatx4*)dH)[3] = h3;
            ((floatx4*)dL)[0] = l0; ((floatx4*)dL)[1] = l1; ((floatx4*)dL)[2] = l2; ((floatx4*)dL)[3] = l3;
        }
        __syncthreads();

        const int cbase = z * 2048 + it * 128;
#pragma unroll
        for (int nt = 0; nt < 8; ++nt) {
            const char* pB = lds + (nt * 16 + cl) * 144 + q * 16;
            short8 bH0 = *(const short8*)(pB);
            short8 bH1 = *(const short8*)(pB + 64);
            short8 bL0 = *(const short8*)(pB + 128 * 144);
            short8 bL1 = *(const short8*)(pB + 128 * 144 + 64);

            floatx4 acc0 = {0.f, 0.f, 0.f, 0.f};
            floatx4 acc1 = {0.f, 0.f, 0.f, 0.f};
            acc0 = MFMA(aH00, bH0, acc0);  acc1 = MFMA(aH10, bH0, acc1);
            acc0 = MFMA(aH01, bH1, acc0);  acc1 = MFMA(aH11, bH1, acc1);
            acc0 = MFMA(aH00, bL0, acc0);  acc1 = MFMA(aH10, bL0, acc1);
            acc0 = MFMA(aH01, bL1, acc0);  acc1 = MFMA(aH11, bL1, acc1);
            acc0 = MFMA(aL00, bH0, acc0);  acc1 = MFMA(aL10, bH0, acc1);
            acc0 = MFMA(aL01, bH1, acc0);  acc1 = MFMA(aL11, bH1, acc1);

            const int idx = cbase + nt * 16 + cl;
#pragma unroll
            for (int i = 0; i < 4; ++i) { UPD(acc0[i], i); UPD(acc1[i], 4 + i); }
        }
    }

    // block reduction: per-lane top-2 (col-slice cl) -> per-row top-2 of 2048
    __syncthreads();
    float* redv = (float*)lds;
    int*   redi = (int*)(lds + 128 * 33 * 4);
#pragma unroll
    for (int s = 0; s < 8; ++s) {
        int rowl = w * 32 + ((s & 4) << 2) + q * 4 + (s & 3);   // +16 when s>=4
        int base = rowl * 33 + cl * 2;
        redv[base]     = b1v[s]; redi[base]     = b1i[s];
        redv[base + 1] = b2v[s]; redi[base + 1] = b2i[s];
    }
    __syncthreads();
    if (tid < 128) {
        float v1 = -INFINITY, v2 = -INFINITY; int i1 = 0x7fffffff, i2 = 0x7fffffff;
        for (int e = 0; e < 32; ++e) {
            float v = redv[tid * 33 + e]; int id = redi[tid * 33 + e];
            if (v > v1 || (v == v1 && id < i1)) { v2 = v1; i2 = i1; v1 = v; i1 = id; }
            else if (v > v2 || (v == v2 && id < i2)) { v2 = v; i2 = id; }
        }
        size_t p = ((size_t)(f * 4 + z)) * ROWS + r0 + tid;
        pi1[p] = i1; pi2[p] = i2;
    }
}

// ---------------- 5. f64 rescore of the 8 candidates/row, emit int32 index ----------------
__global__ __launch_bounds__(256) void rescore_kernel(
    const double* __restrict__ featD,
    const float* __restrict__ cbA, const float* __restrict__ cbP,
    const int* __restrict__ pi1, const int* __restrict__ pi2,
    int* __restrict__ out)
{
    const int tid = threadIdx.x;
    const int lane = tid & 63, wave = tid >> 6;
    const int task = blockIdx.x * 4 + wave;           // 0 .. 2*ROWS-1
    const int f = task / ROWS;
    const int row = task - f * ROWS;
    const float* cb = f ? cbP : cbA;
    const double fd = featD[((size_t)f * ROWS + row) * VQD + lane];
    double bestv = -1.0e300; int besti = 0x7fffffff;
    for (int c = 0; c < 8; ++c) {
        int z = c >> 1;
        size_t p = ((size_t)(f * 4 + z)) * ROWS + row;
        int idx = (c & 1) ? pi2[p] : pi1[p];
        double cv = (double)cb[(size_t)idx * VQD + lane];
        double t = fd * cv, s = cv * cv;
        for (int m = 32; m >= 1; m >>= 1) {
            t += __shfl_xor(t, m, 64);
            s += __shfl_xor(s, m, 64);
        }
        double sim = t / sqrt(s);
        if (sim > bestv || (sim == bestv && idx < besti)) { bestv = sim; besti = idx; }
    }
    if (lane == 0) out[task] = besti;
}

// ---------------- launch ----------------
extern "C" void kernel_launch(void* const* d_in, const int* in_sizes, int n_in,
                              void* d_out, int out_size, void* d_ws, size_t ws_size,
                              hipStream_t stream)
{
    const float* x     = (const float*)d_in[0];
    const float* projA = (const float*)d_in[1];
    const float* projP = (const float*)d_in[2];
    const float* cbA   = (const float*)d_in[3];
    const float* cbP   = (const float*)d_in[4];

    char* ws = (char*)d_ws;
    double*         cosT  = (double*)(ws + OFF_COS);
    double*         sinT  = (double*)(ws + OFF_SIN);
    unsigned short* ftH   = (unsigned short*)(ws + OFF_FTH);
    unsigned short* ftL   = (unsigned short*)(ws + OFF_FTL);
    unsigned short* cbHp  = (unsigned short*)(ws + OFF_CBH);
    unsigned short* cbLp  = (unsigned short*)(ws + OFF_CBL);
    double*         featD = (double*)(ws + OFF_FD);
    int*            pi1   = (int*)(ws + OFF_PI1);
    int*            pi2   = (int*)(ws + OFF_PI2);

    twiddle_kernel<<<1, 256, 0, stream>>>(cosT, sinT);
    dft_proj_kernel<<<ROWS / 8, 128, 0, stream>>>(x, projA, projP, cosT, sinT, ftH, ftL, featD);
    cb_prep_kernel<<<dim3(NEMB / 64, 2), 256, 0, stream>>>(cbA, cbP, cbHp, cbLp);
    argmax_kernel<<<dim3(ROWS / 128, 2, 4), 256, 0, stream>>>(ftH, ftL, cbHp, cbLp, pi1, pi2);
    rescore_kernel<<<(2 * ROWS) / 4, 256, 0, stream>>>(featD, cbA, cbP, pi1, pi2, (int*)d_out);
}